// Round 9
// baseline (465.089 us; speedup 1.0000x reference)
//
#include <hip/hip_runtime.h>
#include <cstdint>
#include <cstddef>

// ---------------------------------------------------------------------------
// GraphAttentionHead: out = elu(softmax(mask(LeakyReLU(mu_i + xi_j))) @ h)
// Round 20: OCCUPANCY via small blocks — 3 blocks/CU (3 waves/SIMD).
//   R14/R16/R18/R19 invariance: every 512-thread gatt = 1 block/CU =
//   2 waves/SIMD, and R17's profile showed that regime is latency-dead
//   (all pipes <10%). 4 waves/SIMD needs <=128 VGPR (impossible, R12) but
//   3 waves/SIMD needs <=170 (pool ~512/SIMD, m69 quantization).
//   k_gatt14: block 64i x 1024j, 256 thr (4 waves x 16i), wave 16i x 256n,
//   acc[16]=64 VGPR, live ~130 <= 170 (launch_bounds(256,3)). LDS 40KB
//   (Bs dbuf 2x16KB + E/F 8KB) -> 3 blocks/CU = 12 waves from 3 INDEPENDENT
//   blocks: barrier drains of one block are hidden by the other two
//   (bitmaskz's mechanism). Sync skeleton = R14 dbuf/syncthreads verbatim;
//   occupancy is the only variable. grid 1024 = 8jb x 128ig.
// ---------------------------------------------------------------------------

#define LOG2E 1.44269504f

typedef __attribute__((ext_vector_type(8))) short short8;   // 8 bf16 = 4 VGPRs
typedef __attribute__((ext_vector_type(4))) float floatx4;  // MFMA acc

using uint_as1 = __attribute__((address_space(1))) unsigned int;
using uint_as3 = __attribute__((address_space(3))) unsigned int;

__device__ __forceinline__ void gld_lds16(const void* g, void* l) {
  __builtin_amdgcn_global_load_lds((const uint_as1*)g, (uint_as3*)l, 16, 0, 0);
}

__device__ __forceinline__ unsigned short f2b(float f) {  // fp32 -> bf16 RNE (finite)
  unsigned u = __float_as_uint(f);
  u += 0x7fffu + ((u >> 16) & 1u);
  return (unsigned short)(u >> 16);
}
__device__ __forceinline__ float b2f(short s) {
  return __uint_as_float(((unsigned)(unsigned short)s) << 16);
}

// packed RNE convert: lo16 = bf16(a), hi16 = bf16(b) — single VALU op
__device__ __forceinline__ unsigned cvtpk_bf16(float a, float b) {
  unsigned r;
  asm("v_cvt_pk_bf16_f32 %0, %1, %2" : "=v"(r) : "v"(a), "v"(b));
  return r;
}

// --------------------------- K0a: features -> bf16 -------------------------
__global__ void k_cvt_features(const float* __restrict__ f, unsigned short* __restrict__ fb) {
  int tid = blockIdx.x * 256 + threadIdx.x;
  float4 v = ((const float4*)f)[tid];
  ushort4 o = {f2b(v.x), f2b(v.y), f2b(v.z), f2b(v.w)};
  *(ushort4*)&fb[tid * 4] = o;
}

// ------------------- K0b: W_phi [512][256] -> Wt bf16 [256][512] ------------
__global__ void k_prep_wt(const float* __restrict__ w, unsigned short* __restrict__ wt) {
  int tid = blockIdx.x * 256 + threadIdx.x;
  int n = tid >> 9, k = tid & 511;
  wt[n * 512 + k] = f2b(w[k * 256 + n]);
}

// ----------------- K0c: p_mu = W_phi @ w_mu, p_xi = W_phi @ w_xi ------------
__global__ void k_prep_p(const float* __restrict__ w, const float* __restrict__ wmu,
                         const float* __restrict__ wxi, float* __restrict__ pmu,
                         float* __restrict__ pxi) {
  int tid = blockIdx.x * 256 + threadIdx.x;
  int k = tid >> 2, seg = tid & 3;
  float sm = 0.f, sx = 0.f;
  int base = k * 256 + seg * 64;
#pragma unroll
  for (int c = 0; c < 64; c += 4) {
    float4 wv = *(const float4*)&w[base + c];
    float4 mv = *(const float4*)&wmu[seg * 64 + c];
    float4 xv = *(const float4*)&wxi[seg * 64 + c];
    sm += wv.x * mv.x + wv.y * mv.y + wv.z * mv.z + wv.w * mv.w;
    sx += wv.x * xv.x + wv.y * xv.y + wv.z * xv.z + wv.w * xv.w;
  }
  sm += __shfl_xor(sm, 1); sm += __shfl_xor(sm, 2);
  sx += __shfl_xor(sx, 1); sx += __shfl_xor(sx, 2);
  if (seg == 0) { pmu[k] = sm; pxi[k] = sx; }
}

// --- K2: mu/xi matvec, then store Emu=e^mu, Fmu=e^0.2mu, Exi, Fxi -----------
__global__ void k_mu_xi(const unsigned short* __restrict__ fb, const float* __restrict__ pmu,
                        const float* __restrict__ pxi, float* __restrict__ Emu,
                        float* __restrict__ Fmu, float* __restrict__ Exi,
                        float* __restrict__ Fxi) {
  int w = threadIdx.x >> 6, l = threadIdx.x & 63;
  int i = blockIdx.x * 4 + w;
  short8 fv = *(const short8*)&fb[i * 512 + l * 8];
  float m = 0.f, x = 0.f;
#pragma unroll
  for (int c = 0; c < 8; ++c) {
    float fvf = b2f(fv[c]);
    m = fmaf(fvf, pmu[l * 8 + c], m);
    x = fmaf(fvf, pxi[l * 8 + c], x);
  }
#pragma unroll
  for (int off = 32; off > 0; off >>= 1) {
    m += __shfl_xor(m, off);
    x += __shfl_xor(x, off);
  }
  if (l == 0) {
    float ms = m * LOG2E, xs = x * LOG2E;
    Emu[i] = __builtin_amdgcn_exp2f(ms);
    Fmu[i] = __builtin_amdgcn_exp2f(0.2f * ms);
    Exi[i] = __builtin_amdgcn_exp2f(xs);
    Fxi[i] = __builtin_amdgcn_exp2f(0.2f * xs);
  }
}

// ------------- K1: h_t[n][m] = (features @ W_phi)^T, bf16 MFMA --------------
__global__ __launch_bounds__(256, 2) void k_gemm1(const unsigned short* __restrict__ fb,
                                                  const unsigned short* __restrict__ wt,
                                                  unsigned short* __restrict__ ht) {
  __shared__ __align__(16) unsigned short As[64 * 64];
  __shared__ __align__(16) unsigned short Bs[128 * 64];
  int t = threadIdx.x, w = t >> 6, l = t & 63;
  int bm_ = blockIdx.x >> 1, bn = blockIdx.x & 1;
  int m0 = bm_ * 64, n0 = bn * 128;
  int lr = l >> 3, lg = l & 7, g = lg ^ lr;
  int kg = l >> 4, ln = l & 15;
  floatx4 zero = {0.f, 0.f, 0.f, 0.f};
  floatx4 acc[4][2];
#pragma unroll
  for (int mf = 0; mf < 4; ++mf)
#pragma unroll
    for (int nf = 0; nf < 2; ++nf) acc[mf][nf] = zero;

  for (int it = 0; it < 8; ++it) {
    int k0 = it * 64;
#pragma unroll
    for (int q = 0; q < 2; ++q) {
      int row = w * 16 + q * 8 + lr;
      const void* gp = fb + (size_t)(m0 + row) * 512 + k0 + g * 8;
      int lb = __builtin_amdgcn_readfirstlane((w * 16 + q * 8) * 64);
      gld_lds16(gp, &As[lb]);
    }
#pragma unroll
    for (int q = 0; q < 4; ++q) {
      int row = w * 32 + q * 8 + lr;
      const void* gp = wt + (size_t)(n0 + row) * 512 + k0 + g * 8;
      int lb = __builtin_amdgcn_readfirstlane((w * 32 + q * 8) * 64);
      gld_lds16(gp, &Bs[lb]);
    }
    __syncthreads();
#pragma unroll
    for (int ks = 0; ks < 2; ++ks) {
      int gg = ks * 4 + kg;
      int swz = (gg ^ (ln & 7)) * 8;
      short8 bfr[2];
#pragma unroll
      for (int nf = 0; nf < 2; ++nf)
        bfr[nf] = *(const short8*)&Bs[(w * 32 + nf * 16 + ln) * 64 + swz];
#pragma unroll
      for (int mf = 0; mf < 4; ++mf) {
        short8 afr = *(const short8*)&As[(mf * 16 + ln) * 64 + swz];
#pragma unroll
        for (int nf = 0; nf < 2; ++nf)
          acc[mf][nf] = __builtin_amdgcn_mfma_f32_16x16x32_bf16(afr, bfr[nf], acc[mf][nf], 0, 0, 0);
      }
    }
    __syncthreads();
  }
#pragma unroll
  for (int mf = 0; mf < 4; ++mf)
#pragma unroll
    for (int nf = 0; nf < 2; ++nf) {
      int ng = n0 + w * 32 + nf * 16 + ln;
      int mg = m0 + mf * 16 + kg * 4;
      ushort4 o = {f2b(acc[mf][nf][0]), f2b(acc[mf][nf][1]),
                   f2b(acc[mf][nf][2]), f2b(acc[mf][nf][3])};
      *(ushort4*)&ht[(size_t)ng * 8192 + mg] = o;
    }
}

// ------------- K3: fused attention GEMM; 4-wave blocks, 3 blocks/CU ---------
// grid 1024 = 8 jb x 128 ig. Block 64i x 256n x 1024j, 4 waves i-split;
// wave 16i x 256n, acc[16]=64 VGPR (QUARTERS of 4 bfv). 32 windows x 32j,
// Bs dbuf 2x16KB + E/F 8KB = 40KB LDS -> 3 blocks/CU (12 waves, 3/SIMD,
// cross-block latency hiding). adj per-lane to registers (1 rowset).
// R14-proven dbuf/syncthreads skeleton. VGPR cap 170 (launch_bounds(256,3)).
__global__ __launch_bounds__(256, 3) void k_gatt14(const int* __restrict__ adjm,
                                                   const unsigned short* __restrict__ ht,
                                                   const float* __restrict__ Emu,
                                                   const float* __restrict__ Fmu,
                                                   const float* __restrict__ Exi,
                                                   const float* __restrict__ Fxi,
                                                   float* __restrict__ nump,
                                                   float* __restrict__ zpart) {
  __shared__ __align__(16) unsigned short Bs[2][256 * 32];  // 32 KB
  __shared__ __align__(16) float EfE[1024];                 // 4 KB
  __shared__ __align__(16) float EfF[1024];                 // 4 KB

  int t = threadIdx.x, w = t >> 6, l = t & 63;
  int ln = l & 15, kg = l >> 4;
  int jb = blockIdx.x & 7, ig = blockIdx.x >> 3;
  int i0 = ig * 64;
  int jc0 = jb * 1024;

  // ---- prologue: E/F staging (256 threads: 2KB each of E and F rows) ----
  *(float4*)&EfE[t * 4] = *(const float4*)&Exi[jc0 + t * 4];
  // second half staged by reusing threads (E then F)
  // (E is 1024 floats = 256 float4 = all threads once; same for F)
  {
    *(float4*)&EfF[t * 4] = *(const float4*)&Fxi[jc0 + t * 4];
  }

  float EM = Emu[i0 + w * 16 + ln];
  float FM = Fmu[i0 + w * 16 + ln];

  // per-lane adj stream base: row (w*16 + ln), j-slice kg*8
  const int* ar0 = adjm + (size_t)(i0 + w * 16 + ln) * 8192 + jc0 + kg * 8;

  floatx4 zero = {0.f, 0.f, 0.f, 0.f};
  floatx4 acc[16];
#pragma unroll
  for (int nf = 0; nf < 16; ++nf) acc[nf] = zero;
  float zacc = 0.f;

  // Bs window: 256 n-rows x 32j; 4 gld_lds/wave (4 waves stage 64 rows each).
  // Source granule pre-swizzled so reader slot kg^((n>>1)&3) yields granule kg.
#define STAGE_B(win_, b_)                                                   \
  {                                                                         \
    int j0_ = jc0 + (win_) * 32;                                            \
    _Pragma("unroll")                                                       \
    for (int q = 0; q < 4; ++q) {                                           \
      int rowbase = w * 64 + q * 16;                                        \
      int row = rowbase + (l >> 2);                                         \
      int g = (l & 3) ^ ((row >> 1) & 3);                                   \
      const void* gp = ht + (size_t)row * 8192 + j0_ + g * 8;               \
      int lb = __builtin_amdgcn_readfirstlane((b_) * (256 * 32) + rowbase * 32); \
      gld_lds16(gp, &((unsigned short*)Bs)[lb]);                            \
    }                                                                       \
  }

  STAGE_B(0, 0);
  __syncthreads();  // E/F + stage(0) drained

  for (int win = 0; win < 32; ++win) {
    int buf = win & 1;
    if (win < 31) {
      STAGE_B(win + 1, buf ^ 1);  // overlaps compute on buf (R14 skeleton)
    }
    // adj for this window -> registers
    int joff = win * 32;
    int4 a0 = *(const int4*)(ar0 + joff);
    int4 a1 = *(const int4*)(ar0 + joff + 4);

    // E/F slice for this window (broadcast reads)
    int jl = win * 32 + kg * 8;
    float4 e0 = *(const float4*)&EfE[jl];
    float4 e1 = *(const float4*)&EfE[jl + 4];
    float4 f0 = *(const float4*)&EfF[jl];
    float4 f1 = *(const float4*)&EfF[jl + 4];

    // A-build from register adj (8 j-elems for this lane's row)
    short8 af;
    {
      int av[8] = {a0.x, a0.y, a0.z, a0.w, a1.x, a1.y, a1.z, a1.w};
      float ex[8] = {e0.x, e0.y, e0.z, e0.w, e1.x, e1.y, e1.z, e1.w};
      float fx[8] = {f0.x, f0.y, f0.z, f0.w, f1.x, f1.y, f1.z, f1.w};
      union { unsigned u[4]; short8 s; } cv;
      float zs = 0.f;
#pragma unroll
      for (int p = 0; p < 4; ++p) {
        float m0 = fmaxf(EM * ex[2 * p], FM * fx[2 * p]);
        float m1 = fmaxf(EM * ex[2 * p + 1], FM * fx[2 * p + 1]);
        m0 = (av[2 * p] != 0) ? m0 : 0.f;
        m1 = (av[2 * p + 1] != 0) ? m1 : 0.f;
        zs += m0;
        zs += m1;
        cv.u[p] = cvtpk_bf16(m0, m1);  // lo=elem 2p, hi=elem 2p+1
      }
      zacc += zs;
      af = cv.s;
    }
    // four quarters of 4 B-frags (live bfv = 16 VGPR)
#pragma unroll
    for (int qtr = 0; qtr < 4; ++qtr) {
      short8 bfv[4];
#pragma unroll
      for (int nf = 0; nf < 4; ++nf) {
        int n = qtr * 64 + nf * 16 + ln;
        bfv[nf] = *(const short8*)&Bs[buf][n * 32 + ((kg ^ ((n >> 1) & 3)) * 8)];
      }
#pragma unroll
      for (int nf = 0; nf < 4; ++nf)
        acc[qtr * 4 + nf] = __builtin_amdgcn_mfma_f32_16x16x32_bf16(
            af, bfv[nf], acc[qtr * 4 + nf], 0, 0, 0);
    }
    __syncthreads();  // stage(win+1) drained; reads of buf done
  }
#undef STAGE_B

  // ---- epilogue: z partial (reduce over kg lanes) ----
  {
    float z = zacc;
    z += __shfl_xor(z, 16);
    z += __shfl_xor(z, 32);
    if (l < 16) zpart[(size_t)jb * 8192 + i0 + w * 16 + ln] = z;
  }

  // ---- epilogue: numerator partial (plain stores) ----
  float* np = nump + (size_t)jb * (8192 * 256);
  {
    int rowb = i0 + w * 16 + kg * 4;
#pragma unroll
    for (int r = 0; r < 4; ++r) {
      float* rp = np + (size_t)(rowb + r) * 256;
#pragma unroll
      for (int nf = 0; nf < 16; ++nf)
        rp[nf * 16 + ln] = acc[nf][r];
    }
  }
}

// ---------------- K4: finalize: sum 8 j-partials, /Z, ELU -------------------
__global__ void k_final(const float* __restrict__ nump, const float* __restrict__ zpart,
                        float* __restrict__ out) {
  int tid = blockIdx.x * 256 + threadIdx.x;  // x4 floats
  int i = tid >> 6;
  float z = 0.f;
#pragma unroll
  for (int p = 0; p < 8; ++p) z += zpart[(size_t)p * 8192 + i];
  float zi = 1.0f / z;
  float4 v = {0.f, 0.f, 0.f, 0.f};
#pragma unroll
  for (int p = 0; p < 8; ++p) {
    float4 s = *(const float4*)&nump[(size_t)p * (8192 * 256) + tid * 4];
    v.x += s.x; v.y += s.y; v.z += s.z; v.w += s.w;
  }
  v.x *= zi; v.y *= zi; v.z *= zi; v.w *= zi;
  v.x = (v.x > 0.f) ? v.x : (__builtin_amdgcn_exp2f(v.x * LOG2E) - 1.f);
  v.y = (v.y > 0.f) ? v.y : (__builtin_amdgcn_exp2f(v.y * LOG2E) - 1.f);
  v.z = (v.z > 0.f) ? v.z : (__builtin_amdgcn_exp2f(v.z * LOG2E) - 1.f);
  v.w = (v.w > 0.f) ? v.w : (__builtin_amdgcn_exp2f(v.w * LOG2E) - 1.f);
  *(float4*)&out[tid * 4] = v;
}

// ---------------------------------------------------------------------------
extern "C" void kernel_launch(void* const* d_in, const int* in_sizes, int n_in,
                              void* d_out, int out_size, void* d_ws, size_t ws_size,
                              hipStream_t stream) {
  const float* features = (const float*)d_in[0];
  const int* adjm = (const int*)d_in[1];
  const float* W_phi = (const float*)d_in[2];
  const float* w_mu = (const float*)d_in[3];
  const float* w_xi = (const float*)d_in[4];
  float* out = (float*)d_out;

  char* ws = (char*)d_ws;
  unsigned short* fb  = (unsigned short*)(ws + 0);         // 8192x512 bf16 = 8 MB
  unsigned short* ht  = (unsigned short*)(ws + 8388608);   // 256x8192 bf16 = 4 MB
  unsigned short* wt  = (unsigned short*)(ws + 12582912);  // 256x512 bf16 = 256 KB
  float* pmu = (float*)(ws + 12845056);                    // 512 f32
  float* pxi = (float*)(ws + 12847104);                    // 512 f32
  float* Emu = (float*)(ws + 12849152);                    // 8192 f32 each
  float* Fmu = (float*)(ws + 12881920);
  float* Exi = (float*)(ws + 12914688);
  float* Fxi = (float*)(ws + 12947456);
  float* zpart = (float*)(ws + 12980224);                  // 8x8192 f32 = 256 KB
  float* nump = (float*)(ws + 25165824);                   // 8 x 8 MB partials

  k_cvt_features<<<4096, 256, 0, stream>>>(features, fb);
  k_prep_wt<<<512, 256, 0, stream>>>(W_phi, wt);
  k_prep_p<<<8, 256, 0, stream>>>(W_phi, w_mu, w_xi, pmu, pxi);
  k_mu_xi<<<2048, 256, 0, stream>>>(fb, pmu, pxi, Emu, Fmu, Exi, Fxi);
  k_gemm1<<<256, 256, 0, stream>>>(fb, wt, ht);
  k_gatt14<<<1024, 256, 0, stream>>>(adjm, ht, Emu, Fmu, Exi, Fxi, nump, zpart);
  k_final<<<2048, 256, 0, stream>>>(nump, zpart, out);
}

// Round 10
// 447.691 us; speedup vs baseline: 1.0389x; 1.0389x over previous
//
#include <hip/hip_runtime.h>
#include <cstdint>
#include <cstddef>

// ---------------------------------------------------------------------------
// GraphAttentionHead: out = elu(softmax(mask(LeakyReLU(mu_i + xi_j))) @ h)
// Round 21: LAUNCH-COUNT COLLAPSE 7 -> 4 kernels.
//   Ledger: fixed overhead = 275us (R17 anchor); fill explains ~160; the
//   other ~115 fits 7 launches x ~10-15us gap (rocprof.md). gatt-core
//   changes are exhausted (R11-R20 all null); attack the fixed term.
//   - k_gemm1m: reads features f32 directly (reg-stage + cvt_pk ->
//     ds_write_b128, SAME LDS layout/addresses/rounding as before) and
//     computes mu/xi partials in its epilogue (acc IS h): shfl+LDS reduce
//     -> mupart[2][8192], xipart[2][8192]. No atomics.
//   - k_gatt16 = R19 gatt13 core; prologue computes exp2 on the fly from
//     mu/xi partial sums (e^mu factor ~cancels in softmax; ~2.5k exp2/blk).
//   - k_cvt_features, k_mu_xi, k_prep_p deleted. k_prep_wt, k_final kept.
// ---------------------------------------------------------------------------

#define LOG2E 1.44269504f

typedef __attribute__((ext_vector_type(8))) short short8;   // 8 bf16 = 4 VGPRs
typedef __attribute__((ext_vector_type(4))) float floatx4;  // MFMA acc

using uint_as1 = __attribute__((address_space(1))) unsigned int;
using uint_as3 = __attribute__((address_space(3))) unsigned int;

__device__ __forceinline__ void gld_lds16(const void* g, void* l) {
  __builtin_amdgcn_global_load_lds((const uint_as1*)g, (uint_as3*)l, 16, 0, 0);
}

__device__ __forceinline__ unsigned short f2b(float f) {  // fp32 -> bf16 RNE (finite)
  unsigned u = __float_as_uint(f);
  u += 0x7fffu + ((u >> 16) & 1u);
  return (unsigned short)(u >> 16);
}

// packed RNE convert: lo16 = bf16(a), hi16 = bf16(b) — single VALU op
__device__ __forceinline__ unsigned cvtpk_bf16(float a, float b) {
  unsigned r;
  asm("v_cvt_pk_bf16_f32 %0, %1, %2" : "=v"(r) : "v"(a), "v"(b));
  return r;
}

// ------------------- K0b: W_phi [512][256] -> Wt bf16 [256][512] ------------
__global__ void k_prep_wt(const float* __restrict__ w, unsigned short* __restrict__ wt) {
  int tid = blockIdx.x * 256 + threadIdx.x;
  int n = tid >> 9, k = tid & 511;
  wt[n * 512 + k] = f2b(w[k * 256 + n]);
}

// ------ K1: h_t = (features @ W_phi)^T (bf16 MFMA) + mu/xi partials ---------
// A-tile: features f32 -> regs -> cvt_pk bf16 -> ds_write_b128 (same LDS
// layout/addresses as the old gld_lds-from-fb path; same RNE rounding).
// Epilogue: mu/xi partial dot over this block's n-half from the f32 acc.
__global__ __launch_bounds__(256, 2) void k_gemm1m(const float* __restrict__ f,
                                                   const unsigned short* __restrict__ wt,
                                                   const float* __restrict__ wmu,
                                                   const float* __restrict__ wxi,
                                                   unsigned short* __restrict__ ht,
                                                   float* __restrict__ mupart,
                                                   float* __restrict__ xipart) {
  __shared__ __align__(16) unsigned short As[64 * 64];
  __shared__ __align__(16) unsigned short Bs[128 * 64];
  __shared__ float musum[4][64];
  __shared__ float xisum[4][64];
  int t = threadIdx.x, w = t >> 6, l = t & 63;
  int bm_ = blockIdx.x >> 1, bn = blockIdx.x & 1;
  int m0 = bm_ * 64, n0 = bn * 128;
  int lr = l >> 3, lg = l & 7, g = lg ^ lr;
  int kg = l >> 4, ln = l & 15;
  floatx4 zero = {0.f, 0.f, 0.f, 0.f};
  floatx4 acc[4][2];
#pragma unroll
  for (int mf = 0; mf < 4; ++mf)
#pragma unroll
    for (int nf = 0; nf < 2; ++nf) acc[mf][nf] = zero;

  for (int it = 0; it < 8; ++it) {
    int k0 = it * 64;
    // A: features f32 -> bf16 regs -> LDS (slot lg of row holds granule lg^lr)
#pragma unroll
    for (int q = 0; q < 2; ++q) {
      int row = w * 16 + q * 8 + lr;
      const float* fp = f + (size_t)(m0 + row) * 512 + k0 + g * 8;
      float4 v0 = *(const float4*)fp;
      float4 v1 = *(const float4*)(fp + 4);
      uint4 d = {cvtpk_bf16(v0.x, v0.y), cvtpk_bf16(v0.z, v0.w),
                 cvtpk_bf16(v1.x, v1.y), cvtpk_bf16(v1.z, v1.w)};
      *(uint4*)&As[row * 64 + lg * 8] = d;
    }
#pragma unroll
    for (int q = 0; q < 4; ++q) {
      int row = w * 32 + q * 8 + lr;
      const void* gp = wt + (size_t)(n0 + row) * 512 + k0 + g * 8;
      int lb = __builtin_amdgcn_readfirstlane((w * 32 + q * 8) * 64);
      gld_lds16(gp, &Bs[lb]);
    }
    __syncthreads();
#pragma unroll
    for (int ks = 0; ks < 2; ++ks) {
      int gg = ks * 4 + kg;
      int swz = (gg ^ (ln & 7)) * 8;
      short8 bfr[2];
#pragma unroll
      for (int nf = 0; nf < 2; ++nf)
        bfr[nf] = *(const short8*)&Bs[(w * 32 + nf * 16 + ln) * 64 + swz];
#pragma unroll
      for (int mf = 0; mf < 4; ++mf) {
        short8 afr = *(const short8*)&As[(mf * 16 + ln) * 64 + swz];
#pragma unroll
        for (int nf = 0; nf < 2; ++nf)
          acc[mf][nf] = __builtin_amdgcn_mfma_f32_16x16x32_bf16(afr, bfr[nf], acc[mf][nf], 0, 0, 0);
      }
    }
    __syncthreads();
  }
  // C store (bf16, transposed ht layout) — unchanged
#pragma unroll
  for (int mf = 0; mf < 4; ++mf)
#pragma unroll
    for (int nf = 0; nf < 2; ++nf) {
      int ng = n0 + w * 32 + nf * 16 + ln;
      int mg = m0 + mf * 16 + kg * 4;
      ushort4 o = {f2b(acc[mf][nf][0]), f2b(acc[mf][nf][1]),
                   f2b(acc[mf][nf][2]), f2b(acc[mf][nf][3])};
      *(ushort4*)&ht[(size_t)ng * 8192 + mg] = o;
    }
  // mu/xi partials over this block's n-half (cols n0 + w*32 + {ln, 16+ln})
  float wma = wmu[n0 + w * 32 + ln], wmb = wmu[n0 + w * 32 + 16 + ln];
  float wxa = wxi[n0 + w * 32 + ln], wxb = wxi[n0 + w * 32 + 16 + ln];
#pragma unroll
  for (int mf = 0; mf < 4; ++mf)
#pragma unroll
    for (int r = 0; r < 4; ++r) {
      float ms = acc[mf][0][r] * wma + acc[mf][1][r] * wmb;
      float xs = acc[mf][0][r] * wxa + acc[mf][1][r] * wxb;
      ms += __shfl_xor(ms, 1); ms += __shfl_xor(ms, 2);
      ms += __shfl_xor(ms, 4); ms += __shfl_xor(ms, 8);
      xs += __shfl_xor(xs, 1); xs += __shfl_xor(xs, 2);
      xs += __shfl_xor(xs, 4); xs += __shfl_xor(xs, 8);
      if (ln == 0) {
        musum[w][mf * 16 + kg * 4 + r] = ms;
        xisum[w][mf * 16 + kg * 4 + r] = xs;
      }
    }
  __syncthreads();
  if (t < 64) {
    float m_ = musum[0][t] + musum[1][t] + musum[2][t] + musum[3][t];
    mupart[(size_t)bn * 8192 + m0 + t] = m_;
  } else if (t < 128) {
    int r = t - 64;
    float x_ = xisum[0][r] + xisum[1][r] + xisum[2][r] + xisum[3][r];
    xipart[(size_t)bn * 8192 + m0 + r] = x_;
  }
}

// ------------- K3: fused attention GEMM (R19 core + on-the-fly exp) ---------
// grid 256 = 8 jb x 32 ig. Block 256i x 256n x 1024j; 8 waves i-split,
// wave 32i x 256n (mf=2, nf=16 in QUARTERS of 4), acc[2][16]=128 VGPR.
// 32 windows x 32j. Bs (ht) quad-buffered via gld_lds (4x16KB); adj loaded
// per-lane to registers at window top. One barrier per window; steady
// s_waitcnt vmcnt(2). Prologue computes EfE=e^xi, EfF=e^0.2xi, EM=e^mu,
// FM=e^0.2mu from the 2-way partial sums (no precomputed E/F arrays).
__global__ __launch_bounds__(512, 1) void k_gatt16(const int* __restrict__ adjm,
                                                   const unsigned short* __restrict__ ht,
                                                   const float* __restrict__ mupart,
                                                   const float* __restrict__ xipart,
                                                   float* __restrict__ nump,
                                                   float* __restrict__ zpart) {
  __shared__ __align__(16) unsigned short Bs[4][256 * 32];  // 64 KB
  __shared__ __align__(16) float EfE[1024];                 // 4 KB
  __shared__ __align__(16) float EfF[1024];                 // 4 KB

  int t = threadIdx.x, w = t >> 6, l = t & 63;
  int ln = l & 15, kg = l >> 4;
  int jb = blockIdx.x & 7, ig = blockIdx.x >> 3;
  int i0 = ig * 256;
  int jc0 = jb * 1024;

  // ---- prologue: xi -> exp staging (halves: t<256 does E, t>=256 does F) ----
  {
    int t2 = t & 255;
    float4 xa = *(const float4*)&xipart[jc0 + t2 * 4];
    float4 xb = *(const float4*)&xipart[8192 + jc0 + t2 * 4];
    float x0 = (xa.x + xb.x) * LOG2E, x1 = (xa.y + xb.y) * LOG2E;
    float x2 = (xa.z + xb.z) * LOG2E, x3 = (xa.w + xb.w) * LOG2E;
    if (t < 256) {
      EfE[t2 * 4 + 0] = __builtin_amdgcn_exp2f(x0);
      EfE[t2 * 4 + 1] = __builtin_amdgcn_exp2f(x1);
      EfE[t2 * 4 + 2] = __builtin_amdgcn_exp2f(x2);
      EfE[t2 * 4 + 3] = __builtin_amdgcn_exp2f(x3);
    } else {
      EfF[t2 * 4 + 0] = __builtin_amdgcn_exp2f(0.2f * x0);
      EfF[t2 * 4 + 1] = __builtin_amdgcn_exp2f(0.2f * x1);
      EfF[t2 * 4 + 2] = __builtin_amdgcn_exp2f(0.2f * x2);
      EfF[t2 * 4 + 3] = __builtin_amdgcn_exp2f(0.2f * x3);
    }
  }

  float EM[2], FM[2];
#pragma unroll
  for (int mf = 0; mf < 2; ++mf) {
    int i = i0 + w * 32 + mf * 16 + ln;
    float mu = (mupart[i] + mupart[8192 + i]) * LOG2E;
    EM[mf] = __builtin_amdgcn_exp2f(mu);
    FM[mf] = __builtin_amdgcn_exp2f(0.2f * mu);
  }

  // per-lane adj stream bases: rows (w*32 + {0,16} + ln), j-slice kg*8
  const int* ar0 = adjm + (size_t)(i0 + w * 32 + ln) * 8192 + jc0 + kg * 8;
  const int* ar1 = ar0 + (size_t)16 * 8192;

  floatx4 zero = {0.f, 0.f, 0.f, 0.f};
  floatx4 acc[2][16];
#pragma unroll
  for (int mf = 0; mf < 2; ++mf)
#pragma unroll
    for (int nf = 0; nf < 16; ++nf) acc[mf][nf] = zero;
  float zacc[2] = {0.f, 0.f};

  // Bs window: 256 n-rows x 32j; 2 gld_lds/wave. Source granule pre-swizzled
  // so reader slot kg^((n>>1)&3) yields granule kg.
#define STAGE_B(win_, b_)                                                   \
  {                                                                         \
    int j0_ = jc0 + (win_) * 32;                                            \
    _Pragma("unroll")                                                       \
    for (int q = 0; q < 2; ++q) {                                           \
      int rowbase = w * 32 + q * 16;                                        \
      int row = rowbase + (l >> 2);                                         \
      int g = (l & 3) ^ ((row >> 1) & 3);                                   \
      const void* gp = ht + (size_t)row * 8192 + j0_ + g * 8;               \
      int lb = __builtin_amdgcn_readfirstlane((b_) * (256 * 32) + rowbase * 32); \
      gld_lds16(gp, &((unsigned short*)Bs)[lb]);                            \
    }                                                                       \
  }

  STAGE_B(0, 0);
  STAGE_B(1, 1);
  __syncthreads();  // E/F + stage(0,1) drained (one-time full drain)

  for (int win = 0; win < 32; ++win) {
    int bR = win & 3;
    // stage(win) landed; stage(win+1) stays in flight
    if (win < 31) {
      asm volatile("s_waitcnt vmcnt(2)" ::: "memory");
    } else {
      asm volatile("s_waitcnt vmcnt(0)" ::: "memory");
    }
    __builtin_amdgcn_s_barrier();   // all waves' stage(win) landed
    asm volatile("" ::: "memory");  // fence: no LDS reads hoist above barrier

    // adj for this window -> registers (issued early; consumed by A-build)
    int joff = win * 32;
    int4 a0 = *(const int4*)(ar0 + joff);
    int4 a1 = *(const int4*)(ar0 + joff + 4);
    int4 a2 = *(const int4*)(ar1 + joff);
    int4 a3 = *(const int4*)(ar1 + joff + 4);

    // E/F slice for this window (broadcast reads)
    int jl = win * 32 + kg * 8;
    float4 e0 = *(const float4*)&EfE[jl];
    float4 e1 = *(const float4*)&EfE[jl + 4];
    float4 f0 = *(const float4*)&EfF[jl];
    float4 f1 = *(const float4*)&EfF[jl + 4];

    // A-build from register adj
    short8 af[2];
#pragma unroll
    for (int mf = 0; mf < 2; ++mf) {
      int av[8];
      if (mf == 0) {
        av[0] = a0.x; av[1] = a0.y; av[2] = a0.z; av[3] = a0.w;
        av[4] = a1.x; av[5] = a1.y; av[6] = a1.z; av[7] = a1.w;
      } else {
        av[0] = a2.x; av[1] = a2.y; av[2] = a2.z; av[3] = a2.w;
        av[4] = a3.x; av[5] = a3.y; av[6] = a3.z; av[7] = a3.w;
      }
      float ex[8] = {e0.x, e0.y, e0.z, e0.w, e1.x, e1.y, e1.z, e1.w};
      float fx[8] = {f0.x, f0.y, f0.z, f0.w, f1.x, f1.y, f1.z, f1.w};
      float A = EM[mf], F = FM[mf];
      union { unsigned u[4]; short8 s; } cv;
      float zs = 0.f;
#pragma unroll
      for (int p = 0; p < 4; ++p) {
        float m0 = fmaxf(A * ex[2 * p], F * fx[2 * p]);
        float m1 = fmaxf(A * ex[2 * p + 1], F * fx[2 * p + 1]);
        m0 = (av[2 * p] != 0) ? m0 : 0.f;
        m1 = (av[2 * p + 1] != 0) ? m1 : 0.f;
        zs += m0;
        zs += m1;
        cv.u[p] = cvtpk_bf16(m0, m1);  // lo=elem 2p, hi=elem 2p+1
      }
      zacc[mf] += zs;
      af[mf] = cv.s;
    }
    // four quarters of 4 B-frags (live bfv = 16 VGPR)
#pragma unroll
    for (int qtr = 0; qtr < 4; ++qtr) {
      short8 bfv[4];
#pragma unroll
      for (int nf = 0; nf < 4; ++nf) {
        int n = qtr * 64 + nf * 16 + ln;
        bfv[nf] = *(const short8*)&Bs[bR][n * 32 + ((kg ^ ((n >> 1) & 3)) * 8)];
      }
#pragma unroll
      for (int mf = 0; mf < 2; ++mf)
#pragma unroll
        for (int nf = 0; nf < 4; ++nf)
          acc[mf][qtr * 4 + nf] = __builtin_amdgcn_mfma_f32_16x16x32_bf16(
              af[mf], bfv[nf], acc[mf][qtr * 4 + nf], 0, 0, 0);
    }
    // issue next-next window staging (write target 2 windows from readers)
    if (win < 30) {
      STAGE_B(win + 2, (win + 2) & 3);
    }
  }
#undef STAGE_B

  // ---- epilogue: z partial (reduce over kg lanes) ----
#pragma unroll
  for (int mf = 0; mf < 2; ++mf) {
    float z = zacc[mf];
    z += __shfl_xor(z, 16);
    z += __shfl_xor(z, 32);
    if (l < 16) zpart[(size_t)jb * 8192 + i0 + w * 32 + mf * 16 + ln] = z;
  }

  // ---- epilogue: numerator partial (plain stores) ----
  float* np = nump + (size_t)jb * (8192 * 256);
#pragma unroll
  for (int mf = 0; mf < 2; ++mf) {
    int rowb = i0 + w * 32 + mf * 16 + kg * 4;
#pragma unroll
    for (int r = 0; r < 4; ++r) {
      float* rp = np + (size_t)(rowb + r) * 256;
#pragma unroll
      for (int nf = 0; nf < 16; ++nf)
        rp[nf * 16 + ln] = acc[mf][nf][r];
    }
  }
}

// ---------------- K4: finalize: sum 8 j-partials, /Z, ELU -------------------
__global__ void k_final(const float* __restrict__ nump, const float* __restrict__ zpart,
                        float* __restrict__ out) {
  int tid = blockIdx.x * 256 + threadIdx.x;  // x4 floats
  int i = tid >> 6;
  float z = 0.f;
#pragma unroll
  for (int p = 0; p < 8; ++p) z += zpart[(size_t)p * 8192 + i];
  float zi = 1.0f / z;
  float4 v = {0.f, 0.f, 0.f, 0.f};
#pragma unroll
  for (int p = 0; p < 8; ++p) {
    float4 s = *(const float4*)&nump[(size_t)p * (8192 * 256) + tid * 4];
    v.x += s.x; v.y += s.y; v.z += s.z; v.w += s.w;
  }
  v.x *= zi; v.y *= zi; v.z *= zi; v.w *= zi;
  v.x = (v.x > 0.f) ? v.x : (__builtin_amdgcn_exp2f(v.x * LOG2E) - 1.f);
  v.y = (v.y > 0.f) ? v.y : (__builtin_amdgcn_exp2f(v.y * LOG2E) - 1.f);
  v.z = (v.z > 0.f) ? v.z : (__builtin_amdgcn_exp2f(v.z * LOG2E) - 1.f);
  v.w = (v.w > 0.f) ? v.w : (__builtin_amdgcn_exp2f(v.w * LOG2E) - 1.f);
  *(float4*)&out[tid * 4] = v;
}

// ---------------------------------------------------------------------------
extern "C" void kernel_launch(void* const* d_in, const int* in_sizes, int n_in,
                              void* d_out, int out_size, void* d_ws, size_t ws_size,
                              hipStream_t stream) {
  const float* features = (const float*)d_in[0];
  const int* adjm = (const int*)d_in[1];
  const float* W_phi = (const float*)d_in[2];
  const float* w_mu = (const float*)d_in[3];
  const float* w_xi = (const float*)d_in[4];
  float* out = (float*)d_out;

  char* ws = (char*)d_ws;
  unsigned short* ht  = (unsigned short*)(ws + 0);         // 256x8192 bf16 = 4 MB
  unsigned short* wt  = (unsigned short*)(ws + 4194304);   // 256x512 bf16 = 256 KB
  float* mupart = (float*)(ws + 4456448);                  // 2x8192 f32 = 64 KB
  float* xipart = (float*)(ws + 4521984);                  // 2x8192 f32 = 64 KB
  float* zpart  = (float*)(ws + 4587520);                  // 8x8192 f32 = 256 KB
  float* nump   = (float*)(ws + 8388608);                  // 8 x 8 MB partials

  k_prep_wt<<<512, 256, 0, stream>>>(W_phi, wt);
  k_gemm1m<<<256, 256, 0, stream>>>(features, wt, w_mu, w_xi, ht, mupart, xipart);
  k_gatt16<<<256, 512, 0, stream>>>(adjm, ht, mupart, xipart, nump, zpart);
  k_final<<<2048, 256, 0, stream>>>(nump, zpart, out);
}